// Round 3
// baseline (396.790 us; speedup 1.0000x reference)
//
#include <hip/hip_runtime.h>
#include <hip/hip_bf16.h>

#define NTOK 65536   // B*S = 64*1024
#define CIN  768
#define NDIM 8
#define NLVL 15
#define NSLOT 8      // KDE atomic slot arrays (contention spread)

// ---------------------------------------------------------------------------
// Kernel A (round-4 restructure): thread <-> (token, channel-half).
//  - Each block: 128 tokens, 4 waves. Wave w: token pane pr=w>>1 (64 tokens),
//    channel half hf=w&1 (384 channels). Lane l owns token pane*64+l.
//  - Weights are WAVE-UNIFORM (hf is per-wave, forced scalar via
//    readfirstlane) -> compiler emits s_load + v_cvt_f64_f32 from SGPR:
//    zero VGPR weight residency, no 96-reg array, no (256,2)-spill cliff.
//  - No shuffle collapse: one LDS cross-wave f64 add replaces the 6-level
//    f64 __shfl_xor tree that serialized per token (round 0-2 latency bound).
//  - z reads: 16B loads from own token row, 8 per 128B line issued as one
//    batch (MSHR-merged, 1 HBM fetch per line, no L1-capacity dependence).
//  - KDE phase 2: 2x120 threads own (pane,d,l), loop 64 tokens from LDS zc
//    (f32 exp, f64 accumulate), one atomic each. No block reduce.
// round-1 lesson: >~230 live VGPRs at (256,2) = spill catastrophe (422MB).
//   This structure holds ~110 VGPRs: cur/nxt 64 + acc 16 + temps.
// round-2 lesson: f32 exp validated (absmax identical 2^-11); exp was never
//   the bottleneck -> attack latency structure instead.
// ---------------------------------------------------------------------------
__global__ __launch_bounds__(256, 2)
void fsq_compress_kde(const float* __restrict__ z, const float* __restrict__ Wc,
                      const float* __restrict__ bc, const float* __restrict__ centers,
                      float* out, double* __restrict__ kde_slots)
{
    const int lane = threadIdx.x & 63;
    const int wv   = threadIdx.x >> 6;     // 0..3
    const int pr   = wv >> 1;              // token pane (0/1) of this wave
    const int hf   = wv & 1;               // channel half (0/1) of this wave
    const int tok  = blockIdx.x * 128 + pr * 64 + lane;

    // wave-uniform channel base, forced into SGPR so weight reads scalarize
    const int cbase = __builtin_amdgcn_readfirstlane(hf * 384);
    const float* __restrict__ wbase = Wc + cbase;

    double acc[NDIM];
#pragma unroll
    for (int d = 0; d < NDIM; ++d) acc[d] = 0.0;

    const float* zrow = z + (size_t)tok * CIN + cbase;

    // prefetch group 0 (32 ch = one 128B line per lane, 8 x float4)
    float4 cur[8], nxt[8];
#pragma unroll
    for (int i = 0; i < 8; ++i) cur[i] = *(const float4*)(zrow + i * 4);

#pragma unroll 1
    for (int g = 0; g < 12; ++g) {
        const int gn = g < 11 ? g + 1 : 11;   // tail reloads itself (L1-hit)
#pragma unroll
        for (int i = 0; i < 8; ++i)
            nxt[i] = *(const float4*)(zrow + gn * 32 + i * 4);

#pragma unroll
        for (int i = 0; i < 8; ++i) {
            const double x0 = (double)cur[i].x;
            const double x1 = (double)cur[i].y;
            const double x2 = (double)cur[i].z;
            const double x3 = (double)cur[i].w;
#pragma unroll
            for (int d = 0; d < NDIM; ++d) {
                const float* wr = wbase + d * CIN + g * 32 + i * 4;  // uniform
                acc[d] = fma(x0, (double)wr[0], acc[d]);
                acc[d] = fma(x1, (double)wr[1], acc[d]);
                acc[d] = fma(x2, (double)wr[2], acc[d]);
                acc[d] = fma(x3, (double)wr[3], acc[d]);
            }
        }
#pragma unroll
        for (int i = 0; i < 8; ++i) cur[i] = nxt[i];
    }

    // cross-wave (half) reduce via LDS; pad to 9 to break 16-word stride
    __shared__ double red[2][64][NDIM + 1];     // 9.2 KiB
    __shared__ float  zc32[128][NDIM + 1];      // 4.6 KiB
    if (hf == 1) {
#pragma unroll
        for (int d = 0; d < NDIM; ++d) red[pr][lane][d] = acc[d];
    }
    __syncthreads();

    if (hf == 0) {
        double zc[NDIM];
#pragma unroll
        for (int d = 0; d < NDIM; ++d)
            zc[d] = acc[d] + red[pr][lane][d] + (double)bc[d];

        // stash f64 zc into the 64B row head of out (read by kernel C)
        double* orow = (double*)(out + (size_t)tok * CIN);
#pragma unroll
        for (int d = 0; d < NDIM; d += 2) {
            double2 v; v.x = zc[d]; v.y = zc[d + 1];
            *(double2*)(orow + d) = v;
        }
#pragma unroll
        for (int d = 0; d < NDIM; ++d) zc32[pr * 64 + lane][d] = (float)zc[d];
    }
    __syncthreads();

    // phase 2: KDE. thread -> (token pane, dim, level); 64 tokens each.
    const int grp = threadIdx.x >> 7;      // token pane
    const int idx = threadIdx.x & 127;
    const int d2  = idx >> 4;
    const int l2  = idx & 15;
    if (l2 < NLVL) {
        const float c = centers[d2 * NLVL + l2];
        double k = 0.0;
#pragma unroll 4
        for (int t = 0; t < 64; ++t) {
            const float s  = zc32[grp * 64 + t][d2];
            const float df = c - s;
            k += (double)__expf(df * df * -2.0f);   // exp(-0.5*((c-s)/0.5)^2)
        }
        double* slot = kde_slots + (blockIdx.x & (NSLOT - 1)) * 128;
        unsafeAtomicAdd(&slot[d2 * NLVL + l2], k);
    }
}

// ---------------------------------------------------------------------------
// Kernel C: recompute scaled centers in LDS (fused scale step), f64 argmin
// per (token, dim), fp32 expand z_q = q @ We^T + be. Reads zc from the row
// heads this wave later overwrites (load-before-store within the wave).
// launch_bounds(256,2): We's 96-reg array must not spill (round-2 lesson).
// ---------------------------------------------------------------------------
__global__ __launch_bounds__(256, 2)
void fsq_quant_expand(const double* __restrict__ kde_slots,
                      const float* __restrict__ centers,
                      const float* __restrict__ We, const float* __restrict__ be,
                      float* out, float* out_scalar)
{
    __shared__ double w_lds[NDIM * NLVL];
    __shared__ double sc_lds[NDIM * NLVL];
    {
        const int t = threadIdx.x;
        if (t < NDIM * NLVL) {
            double a = 0.0;
#pragma unroll
            for (int k = 0; k < NSLOT; ++k) a += kde_slots[k * 128 + t];
            w_lds[t] = a * (1.0 / 65536.0) + 1e-6;
        }
        __syncthreads();
        if (t < NDIM * NLVL) {
            const int d = t / NLVL;
            double s = 0.0;
#pragma unroll
            for (int l = 0; l < NLVL; ++l) s += w_lds[d * NLVL + l];
            sc_lds[t] = (double)centers[t] * (w_lds[t] / s);
        }
        if (blockIdx.x == 0 && t == 0) *out_scalar = 0.0f;
        __syncthreads();
    }

    const int lane  = threadIdx.x & 63;
    const int gwave = blockIdx.x * 4 + (threadIdx.x >> 6);
    const int base  = gwave * 8;

    // We in fp32 regs: channel c = lane*4 + 256*m + k
    float Wer[12][NDIM];
    float ber[12];
#pragma unroll
    for (int m = 0; m < 3; ++m) {
#pragma unroll
        for (int k = 0; k < 4; ++k) {
            const int    c  = lane * 4 + 256 * m + k;
            const float4 u0 = *(const float4*)(We + c * NDIM);
            const float4 u1 = *(const float4*)(We + c * NDIM + 4);
            Wer[m * 4 + k][0] = u0.x; Wer[m * 4 + k][1] = u0.y;
            Wer[m * 4 + k][2] = u0.z; Wer[m * 4 + k][3] = u0.w;
            Wer[m * 4 + k][4] = u1.x; Wer[m * 4 + k][5] = u1.y;
            Wer[m * 4 + k][6] = u1.z; Wer[m * 4 + k][7] = u1.w;
            ber[m * 4 + k] = be[c];
        }
    }

    const int dsel = lane & 7;      // this lane's dim
    const int tsel = lane >> 3;     // this lane's token within the group of 8

    // one zc value per lane: (token base+tsel, dim dsel) — before any store
    double zd;
    __builtin_memcpy(&zd, out + (size_t)(base + tsel) * CIN + 2 * dsel, 8);

    // first-min argmin over the 15 scaled centers of dim dsel (matches np)
    const double* sc = sc_lds + dsel * NLVL;
    double best = fabs(zd - sc[0]);
    double q    = sc[0];
#pragma unroll
    for (int l = 1; l < NLVL; ++l) {
        const double dd = fabs(zd - sc[l]);
        if (dd < best) { best = dd; q = sc[l]; }
    }
    const float qf = (float)q;

#pragma unroll 1
    for (int t = 0; t < 8; ++t) {
        float qa[NDIM];
#pragma unroll
        for (int j = 0; j < NDIM; ++j) qa[j] = __shfl(qf, t * 8 + j, 64);

        float* op = out + (size_t)(base + t) * CIN;
#pragma unroll
        for (int m = 0; m < 3; ++m) {
            float v[4];
#pragma unroll
            for (int k = 0; k < 4; ++k) {
                float s = ber[m * 4 + k];
#pragma unroll
                for (int j = 0; j < NDIM; ++j)
                    s = fmaf(qa[j], Wer[m * 4 + k][j], s);
                v[k] = s;
            }
            *(float4*)(op + m * 256 + lane * 4) = make_float4(v[0], v[1], v[2], v[3]);
        }
    }
}

// ---------------------------------------------------------------------------
extern "C" void kernel_launch(void* const* d_in, const int* in_sizes, int n_in,
                              void* d_out, int out_size, void* d_ws, size_t ws_size,
                              hipStream_t stream)
{
    const float* z       = (const float*)d_in[0];
    const float* Wc      = (const float*)d_in[1];
    const float* bc      = (const float*)d_in[2];
    const float* We      = (const float*)d_in[3];
    const float* be      = (const float*)d_in[4];
    const float* centers = (const float*)d_in[5];
    float*       out     = (float*)d_out;

    double* kde_slots = (double*)d_ws;   // NSLOT x 128 doubles = 8 KB

    hipMemsetAsync(kde_slots, 0, NSLOT * 128 * sizeof(double), stream);
    fsq_compress_kde<<<512, 256, 0, stream>>>(z, Wc, bc, centers, out, kde_slots);
    fsq_quant_expand<<<2048, 256, 0, stream>>>(kde_slots, centers, We, be, out,
                                               out + (size_t)out_size - 1);
}